// Round 1
// baseline (3366.871 us; speedup 1.0000x reference)
//
#include <hip/hip_runtime.h>
#include <hip/hip_fp8.h>
#include <cmath>

// Problem constants
#define NROWS 16384
#define KDIM  16384
#define IN_F  512
#define HID   256
#define OUT_F 16
#define NSTEPS 16
#define SIGMA2 0.1f

// fp8 scaling: L entries ~N(0, 1/N^2) (std ~6.1e-5). Scale by 4096 (exact pow2)
// -> std ~0.25, max ~1.5: well inside e4m3 range with good mantissa use.
// u entries ~O(1), max ~6. Scale by 16 -> max ~100 << 448.
#define SCALE_L 4096.0f
#define SCALE_U 16.0f
#define ALPHA (SIGMA2 / (SCALE_L * SCALE_U))

typedef float f32x4 __attribute__((ext_vector_type(4)));

__device__ __forceinline__ unsigned char to_fp8(float x) {
    __hip_fp8_e4m3 t(x);  // OCP e4m3fn, RNE + satfinite
    return (unsigned char)t.__x;
}

// ---------------------------------------------------------------------------
// Kernel 1: L (fp32, 1 GiB) -> L8 (e4m3 * SCALE_L, 256 MiB). Pure BW.
// ---------------------------------------------------------------------------
__global__ void convert_L_kernel(const float* __restrict__ L,
                                 unsigned char* __restrict__ L8) {
    const long total = (long)NROWS * KDIM / 4;  // float4 count
    long i = (long)blockIdx.x * blockDim.x + threadIdx.x;
    const long stride = (long)gridDim.x * blockDim.x;
    const float4* __restrict__ in4 = (const float4*)L;
    unsigned int* __restrict__ out4 = (unsigned int*)L8;
    for (; i < total; i += stride) {
        float4 v = in4[i];
        unsigned int p = (unsigned int)to_fp8(v.x * SCALE_L)
                       | ((unsigned int)to_fp8(v.y * SCALE_L) << 8)
                       | ((unsigned int)to_fp8(v.z * SCALE_L) << 16)
                       | ((unsigned int)to_fp8(v.w * SCALE_L) << 24);
        out4[i] = p;
    }
}

// ---------------------------------------------------------------------------
// Kernel 2: fused MLP head. u0 = feat@Ws + bs + elu(feat@W1+b1)@W2 + b2.
// 32 rows per block (feat tile 64 KiB LDS). fp32 vector math (4.3 GFLOP).
// Writes u0 (fp32, row-major) and u8T (e4m3, column-major [16][16384]).
// ---------------------------------------------------------------------------
__global__ __launch_bounds__(256) void mlp_kernel(
    const float* __restrict__ feat,
    const float* __restrict__ W1, const float* __restrict__ b1,
    const float* __restrict__ W2, const float* __restrict__ b2,
    const float* __restrict__ Ws, const float* __restrict__ bs,
    float* __restrict__ u_out, unsigned char* __restrict__ u8T_out) {
    __shared__ __align__(16) float ftile[32 * 512];  // 64 KiB; reused for h
    const int t = threadIdx.x;
    const long rowbase = (long)blockIdx.x * 32;

    // Stage 32 feature rows, coalesced float4
    {
        const float4* __restrict__ f4 = (const float4*)(feat + rowbase * IN_F);
        float4* s4 = (float4*)ftile;
        #pragma unroll
        for (int i = 0; i < 16; ++i) s4[i * 256 + t] = f4[i * 256 + t];
    }
    __syncthreads();

    // h[r][t] for r=0..31 (thread t owns hidden unit t)
    float acc[32];
    #pragma unroll
    for (int r = 0; r < 32; ++r) acc[r] = b1[t];
    for (int k = 0; k < IN_F; k += 4) {
        const float w0 = W1[(k + 0) * HID + t];
        const float w1 = W1[(k + 1) * HID + t];
        const float w2 = W1[(k + 2) * HID + t];
        const float w3 = W1[(k + 3) * HID + t];
        #pragma unroll
        for (int r = 0; r < 32; ++r) {
            const float4 f = *(const float4*)&ftile[r * 512 + k];
            float a = acc[r];
            a = fmaf(f.x, w0, a);
            a = fmaf(f.y, w1, a);
            a = fmaf(f.z, w2, a);
            a = fmaf(f.w, w3, a);
            acc[r] = a;
        }
    }
    #pragma unroll
    for (int r = 0; r < 32; ++r)
        acc[r] = acc[r] > 0.0f ? acc[r] : expm1f(acc[r]);  // elu, alpha=1

    // Shortcut path: feat@Ws + biases. 512 outputs, 2 per thread.
    float sv[2];
    #pragma unroll
    for (int rep = 0; rep < 2; ++rep) {
        const int idx = rep * 256 + t;
        const int r = idx >> 4, c = idx & 15;
        float s = bs[c] + b2[c];
        for (int k = 0; k < IN_F; k += 4) {
            const float4 f = *(const float4*)&ftile[r * 512 + k];
            s = fmaf(f.x, Ws[(k + 0) * OUT_F + c], s);
            s = fmaf(f.y, Ws[(k + 1) * OUT_F + c], s);
            s = fmaf(f.z, Ws[(k + 2) * OUT_F + c], s);
            s = fmaf(f.w, Ws[(k + 3) * OUT_F + c], s);
        }
        sv[rep] = s;
    }
    __syncthreads();
    // Overwrite LDS with h tile, stride 257 to avoid bank conflicts
    #pragma unroll
    for (int r = 0; r < 32; ++r) ftile[r * 257 + t] = acc[r];
    __syncthreads();
    // + h@W2, then write u0 and quantized transposed u8T
    #pragma unroll
    for (int rep = 0; rep < 2; ++rep) {
        const int idx = rep * 256 + t;
        const int r = idx >> 4, c = idx & 15;
        float s = sv[rep];
        for (int j = 0; j < HID; ++j)
            s = fmaf(ftile[r * 257 + j], W2[j * OUT_F + c], s);
        const long gr = rowbase + r;
        u_out[gr * OUT_F + c] = s;
        if (u8T_out) u8T_out[(long)c * NROWS + gr] = to_fp8(s * SCALE_U);
    }
}

// ---------------------------------------------------------------------------
// Kernel 3: one diffusion step via fp8 MFMA.
// Block = 512 threads = 8 waves; block owns one 16-row tile of L; wave w owns
// K-chunk [w*2048, (w+1)*2048). A frag: lane(q=lane>>4, r=lane&15) loads 8
// contiguous bytes of L8 row r at k = kb + 8q. B frag: same k from u8T col n.
// C/D layout: col=lane&15, row=(lane>>4)*4+reg (HW-verified, dtype-indep).
// ---------------------------------------------------------------------------
__global__ __launch_bounds__(512) void diff_step_fp8(
    const unsigned char* __restrict__ L8,
    const float* __restrict__ u_in,
    const unsigned char* __restrict__ u8T_in,
    float* __restrict__ u_out,
    unsigned char* __restrict__ u8T_out) {
    const int t = threadIdx.x;
    const int lane = t & 63;
    const int wv = t >> 6;        // 0..7
    const int q = lane >> 4;      // 0..3
    const int rn = lane & 15;     // A: row within tile; B: u column
    const long tile = blockIdx.x; // 0..1023

    const long kbase = (long)wv * 2048;
    const unsigned long long* __restrict__ Ap =
        (const unsigned long long*)(L8 + (tile * 16 + rn) * (long)KDIM + kbase) + q;
    const unsigned long long* __restrict__ Bp =
        (const unsigned long long*)(u8T_in + (long)rn * KDIM + kbase) + q;

    f32x4 acc = {0.f, 0.f, 0.f, 0.f};
    #pragma unroll 8
    for (int i = 0; i < 64; ++i) {  // 64 MFMAs of K=32 -> 2048
        const long a = (long)Ap[(long)i * 4];  // +32 B per iter
        const long b = (long)Bp[(long)i * 4];
        acc = __builtin_amdgcn_mfma_f32_16x16x32_fp8_fp8(a, b, acc, 0, 0, 0);
    }

    __shared__ float red[8][16][16];
    #pragma unroll
    for (int rg = 0; rg < 4; ++rg) red[wv][q * 4 + rg][rn] = acc[rg];
    __syncthreads();
    if (t < 256) {
        const int r = t >> 4, c = t & 15;
        float s = 0.f;
        #pragma unroll
        for (int w = 0; w < 8; ++w) s += red[w][r][c];
        const long gr = tile * 16 + r;
        const float un = u_in[gr * OUT_F + c] - ALPHA * s;
        u_out[gr * OUT_F + c] = un;
        u8T_out[(long)c * NROWS + gr] = to_fp8(un * SCALE_U);
    }
}

// ---------------------------------------------------------------------------
// Fallback: fp32 diffusion step (if workspace too small for L8). Correct,
// slow (~1 GiB/step HBM).
// ---------------------------------------------------------------------------
__global__ __launch_bounds__(256) void diff_step_f32(
    const float* __restrict__ L,
    const float* __restrict__ u_in,
    float* __restrict__ u_out) {
    const long row = (long)blockIdx.x * 16 + (threadIdx.x >> 4);
    const int c = threadIdx.x & 15;
    const float* __restrict__ Lr = L + row * KDIM;
    float s = 0.f;
    for (int k = 0; k < KDIM; ++k) s = fmaf(Lr[k], u_in[k * OUT_F + c], s);
    u_out[row * OUT_F + c] = u_in[row * OUT_F + c] - SIGMA2 * s;
}

// ---------------------------------------------------------------------------
extern "C" void kernel_launch(void* const* d_in, const int* in_sizes, int n_in,
                              void* d_out, int out_size, void* d_ws, size_t ws_size,
                              hipStream_t stream) {
    const float* feat = (const float*)d_in[0];
    const float* L    = (const float*)d_in[1];
    const float* W1   = (const float*)d_in[2];
    const float* b1   = (const float*)d_in[3];
    const float* W2   = (const float*)d_in[4];
    const float* b2   = (const float*)d_in[5];
    const float* Ws   = (const float*)d_in[6];
    const float* bs   = (const float*)d_in[7];
    float* out = (float*)d_out;

    const size_t szL8 = (size_t)NROWS * KDIM;        // 256 MiB
    const size_t szU  = (size_t)NROWS * OUT_F * 4;   // 1 MiB
    const size_t szU8 = (size_t)NROWS * OUT_F;       // 256 KiB
    const size_t need = szL8 + 2 * szU + 2 * szU8;

    if (ws_size >= need) {
        unsigned char* L8 = (unsigned char*)d_ws;
        float* uA = (float*)(L8 + szL8);
        float* uB = uA + (size_t)NROWS * OUT_F;
        unsigned char* q8A = (unsigned char*)(uB + (size_t)NROWS * OUT_F);
        unsigned char* q8B = q8A + szU8;

        convert_L_kernel<<<4096, 256, 0, stream>>>(L, L8);
        mlp_kernel<<<NROWS / 32, 256, 0, stream>>>(feat, W1, b1, W2, b2, Ws, bs,
                                                   uA, q8A);
        float* ui = uA; unsigned char* qi = q8A;
        float* uo = uB; unsigned char* qo = q8B;
        for (int s = 0; s < NSTEPS; ++s) {
            float* uout_p = (s == NSTEPS - 1) ? out : uo;
            diff_step_fp8<<<NROWS / 16, 512, 0, stream>>>(L8, ui, qi, uout_p, qo);
            ui = uout_p; qi = qo;
            uo = (ui == uA) ? uB : uA;
            qo = (qi == q8A) ? q8B : q8A;
        }
    } else {
        // fp32 fallback: only needs 2 MiB of workspace
        float* uA = (float*)d_ws;
        float* uB = uA + (size_t)NROWS * OUT_F;
        mlp_kernel<<<NROWS / 32, 256, 0, stream>>>(feat, W1, b1, W2, b2, Ws, bs,
                                                   uA, (unsigned char*)nullptr);
        float* ui = uA; float* uo = uB;
        for (int s = 0; s < NSTEPS; ++s) {
            float* uout_p = (s == NSTEPS - 1) ? out : uo;
            diff_step_f32<<<NROWS / 16, 256, 0, stream>>>(L, ui, uout_p);
            ui = uout_p;
            uo = (ui == uA) ? uB : uA;
        }
    }
}